// Round 8
// baseline (145.211 us; speedup 1.0000x reference)
//
#include <hip/hip_runtime.h>

#define DD 256   // feature dim
#define N1 512
#define N2 512
#define BB 4

// Packed fp32 via <2 x float> vector IR -> v_pk_*_f32 (R5 taught us: never
// hand-write VOP3P inline asm).
typedef float f2 __attribute__((ext_vector_type(2)));

// ---------------------------------------------------------------------------
// Kernel 1: projection GEMMs (fp32 vector ALU; no fp32 MFMA on CDNA4).
// 64x64 tile / 256 threads / 4x4 outputs per thread (best LDS-bytes/output:
// 32 B LDS read per 16 fma-pairs), packed f2 accumulation, K-chunks of 32
// with register-prefetch double buffering. Grid 256 blocks (1/CU).
// ---------------------------------------------------------------------------
__global__ __launch_bounds__(256) void proj_kernel(
    const float* __restrict__ x, const float* __restrict__ y,
    const float* __restrict__ W1, const float* __restrict__ b1,
    float* __restrict__ xp, float* __restrict__ yp)
{
    const int which = blockIdx.z;
    const float* __restrict__ A  = which ? y : x;
    const float* __restrict__ Bw = W1 + which * DD * DD;
    float* __restrict__ outp = which ? yp : xp;

    __shared__ float As[32 * 68];   // As[k][m] (transposed), stride 68
    __shared__ float Bs[32 * 68];   // Bs[k][n], stride 68

    const int tid = threadIdx.x;
    const int tx = tid & 15, ty = tid >> 4;
    const int mBase = blockIdx.x * 64;
    const int nBase = blockIdx.y * 64;

    const float4* A4 = (const float4*)A;
    const float4* B4 = (const float4*)Bw;

    const int ar = tid >> 2;       // 0..63  A row (m)
    const int ac = tid & 3;        // 0..3   A float4 col (and +4)
    const int br = tid >> 4;       // 0..15  B k-row (and +16)
    const int bc = tid & 15;       // 0..15  B float4 col (n/4)

    float4 pa0, pa1, pb0, pb1;
    pa0 = A4[(mBase + ar) * 64 + ac];
    pa1 = A4[(mBase + ar) * 64 + ac + 4];
    pb0 = B4[br * 64 + (nBase >> 2) + bc];
    pb1 = B4[(br + 16) * 64 + (nBase >> 2) + bc];

    f2 acc[4][2] = {};

    for (int kc = 0; kc < 8; ++kc) {
        __syncthreads();
        {
            float av0[4] = {pa0.x, pa0.y, pa0.z, pa0.w};
            float av1[4] = {pa1.x, pa1.y, pa1.z, pa1.w};
            #pragma unroll
            for (int q = 0; q < 4; ++q) As[(ac * 4 + q) * 68 + ar] = av0[q];
            #pragma unroll
            for (int q = 0; q < 4; ++q) As[((ac + 4) * 4 + q) * 68 + ar] = av1[q];
            *(float4*)&Bs[br * 68 + bc * 4] = pb0;
            *(float4*)&Bs[(br + 16) * 68 + bc * 4] = pb1;
        }
        __syncthreads();
        if (kc < 7) {
            pa0 = A4[(mBase + ar) * 64 + (kc + 1) * 8 + ac];
            pa1 = A4[(mBase + ar) * 64 + (kc + 1) * 8 + ac + 4];
            pb0 = B4[((kc + 1) * 32 + br) * 64 + (nBase >> 2) + bc];
            pb1 = B4[((kc + 1) * 32 + br + 16) * 64 + (nBase >> 2) + bc];
        }
        #pragma unroll
        for (int k = 0; k < 32; ++k) {
            float4 a = *(const float4*)&As[k * 68 + ty * 4];
            float4 b = *(const float4*)&Bs[k * 68 + tx * 4];
            f2 blo = {b.x, b.y};
            f2 bhi = {b.z, b.w};
            float av[4] = {a.x, a.y, a.z, a.w};
            #pragma unroll
            for (int i = 0; i < 4; ++i) {
                f2 ai = {av[i], av[i]};
                acc[i][0] = __builtin_elementwise_fma(ai, blo, acc[i][0]);
                acc[i][1] = __builtin_elementwise_fma(ai, bhi, acc[i][1]);
            }
        }
    }

    f2 blo = {0.f, 0.f}, bhi = {0.f, 0.f};
    if (which == 0) {
        float4 bias = *((const float4*)b1 + (nBase >> 2) + tx);
        blo.x = bias.x; blo.y = bias.y; bhi.x = bias.z; bhi.y = bias.w;
    }
    #pragma unroll
    for (int i = 0; i < 4; ++i) {
        f2 lo = acc[i][0] + blo;
        f2 hi = acc[i][1] + bhi;
        float4 o;
        o.x = lo.x; o.y = lo.y; o.z = hi.x; o.w = hi.y;
        ((float4*)outp)[(mBase + ty * 4 + i) * (DD / 4) + (nBase >> 2) + tx] = o;
    }
}

// ---------------------------------------------------------------------------
// Packed tanh-form gelu pair (same math as R2-R7, absmax 3.9e-3):
//   gelu(h) = h * (1 - 1/(exp2(h*(K1 + K2 h^2)) + 1))
// ---------------------------------------------------------------------------
__device__ __forceinline__ f2 gelu2(f2 h)
{
    f2 h2 = h * h;
    f2 t  = __builtin_elementwise_fma(h2, (f2)0.1029432f, (f2)2.3022083f);
    f2 z  = h * t;
    f2 e;
    e.x = __builtin_amdgcn_exp2f(z.x);
    e.y = __builtin_amdgcn_exp2f(z.y);
    f2 a = e + 1.0f;
    f2 r;
    r.x = __builtin_amdgcn_rcpf(a.x);
    r.y = __builtin_amdgcn_rcpf(a.y);
    return __builtin_elementwise_fma(-h, r, h);   // h - h*r = h*sigmoid(z)
}

// ---------------------------------------------------------------------------
// Kernel 2: o[b,n,m] = sum_d gelu(xp[b,n,d] + yp[b,m,d]) * W2[d] + b2
// 32x32 tile / 256-thread (4-wave) block / 2x2 outputs/thread.
// R8 additions vs R7 (which stalled at VALUBusy 68%, VGPR 36 = zero ILP):
//  - whole W2 chunk (16 x float4, uniform) preloaded into SGPRs per kc:
//    one lgkmcnt wait instead of 16 scattered s_load stalls;
//  - LDS reads software-pipelined by one c4 iteration (explicit xr/yr
//    double-buffer), so each iteration's ~368 VALU cycles hide the next
//    iteration's ds_read latency.
// Stride-68 LDS rows keep reads conflict-free (xr: 16-lane broadcast;
// yr: 2-way aliased = free).
// ---------------------------------------------------------------------------
__global__ __launch_bounds__(256, 4) void cross_kernel(
    const float* __restrict__ xp, const float* __restrict__ yp,
    const float* __restrict__ W2, const float* __restrict__ b2,
    float* __restrict__ o)
{
    __shared__ float xs[32 * 68];
    __shared__ float ys[32 * 68];

    const int tid   = threadIdx.x;
    const int b     = blockIdx.z;
    const int mBase = blockIdx.x * 32;
    const int nBase = blockIdx.y * 32;
    const int tx = tid & 15;       // m sub-index (cols tx, tx+16)
    const int ty = tid >> 4;       // n sub-index (rows ty, ty+16)

    const float4* xp4 = (const float4*)xp + (b * N1 + nBase) * (DD / 4);
    const float4* yp4 = (const float4*)yp + (b * N2 + mBase) * (DD / 4);
    const float4* __restrict__ W2v = (const float4*)W2;

    const int srow = tid >> 4;          // 0..15
    const int sc4  = tid & 15;          // float4 col within chunk

    float4 px[2], py[2];
    px[0] = xp4[srow * 64 + sc4];
    px[1] = xp4[(srow + 16) * 64 + sc4];
    py[0] = yp4[srow * 64 + sc4];
    py[1] = yp4[(srow + 16) * 64 + sc4];

    f2 acc[2][2] = {};

    for (int kc = 0; kc < 4; ++kc) {
        __syncthreads();
        *(float4*)&xs[srow * 68 + sc4 * 4]        = px[0];
        *(float4*)&xs[(srow + 16) * 68 + sc4 * 4] = px[1];
        *(float4*)&ys[srow * 68 + sc4 * 4]        = py[0];
        *(float4*)&ys[(srow + 16) * 68 + sc4 * 4] = py[1];
        __syncthreads();
        if (kc < 3) {
            px[0] = xp4[srow * 64 + (kc + 1) * 16 + sc4];
            px[1] = xp4[(srow + 16) * 64 + (kc + 1) * 16 + sc4];
            py[0] = yp4[srow * 64 + (kc + 1) * 16 + sc4];
            py[1] = yp4[(srow + 16) * 64 + (kc + 1) * 16 + sc4];
        }

        // W2 chunk -> SGPRs (uniform loads), one burst per kc
        float4 wreg[16];
        #pragma unroll
        for (int c4 = 0; c4 < 16; ++c4) wreg[c4] = W2v[kc * 16 + c4];

        // software-pipelined LDS reads (depth 1)
        float4 xr[2][2], yr[2][2];
        #pragma unroll
        for (int i = 0; i < 2; ++i) {
            xr[0][i] = *(const float4*)&xs[(ty + 16 * i) * 68];
            yr[0][i] = *(const float4*)&ys[(tx + 16 * i) * 68];
        }

        #pragma unroll
        for (int c4 = 0; c4 < 16; ++c4) {
            const int cur = c4 & 1, nxt = cur ^ 1;
            if (c4 < 15) {
                #pragma unroll
                for (int i = 0; i < 2; ++i) {
                    xr[nxt][i] = *(const float4*)&xs[(ty + 16 * i) * 68 + (c4 + 1) * 4];
                    yr[nxt][i] = *(const float4*)&ys[(tx + 16 * i) * 68 + (c4 + 1) * 4];
                }
            }
            float4 wv = wreg[c4];
            f2 wlo = {wv.x, wv.y};
            f2 whi = {wv.z, wv.w};
            #pragma unroll
            for (int i = 0; i < 2; ++i) {
                f2 xlo = {xr[cur][i].x, xr[cur][i].y};
                f2 xhi = {xr[cur][i].z, xr[cur][i].w};
                #pragma unroll
                for (int j = 0; j < 2; ++j) {
                    f2 ylo = {yr[cur][j].x, yr[cur][j].y};
                    f2 yhi = {yr[cur][j].z, yr[cur][j].w};
                    f2 glo = gelu2(xlo + ylo);
                    acc[i][j] = __builtin_elementwise_fma(glo, wlo, acc[i][j]);
                    f2 ghi = gelu2(xhi + yhi);
                    acc[i][j] = __builtin_elementwise_fma(ghi, whi, acc[i][j]);
                }
            }
        }
    }

    const float bias2 = b2[0];
    const size_t base = ((size_t)(b * N1 + nBase)) * N2 + mBase;
    #pragma unroll
    for (int i = 0; i < 2; ++i) {
        #pragma unroll
        for (int j = 0; j < 2; ++j) {
            o[base + (size_t)(ty + 16 * i) * N2 + (tx + 16 * j)] =
                acc[i][j].x + acc[i][j].y + bias2;
        }
    }
}

extern "C" void kernel_launch(void* const* d_in, const int* in_sizes, int n_in,
                              void* d_out, int out_size, void* d_ws, size_t ws_size,
                              hipStream_t stream)
{
    const float* x  = (const float*)d_in[0];
    const float* y  = (const float*)d_in[1];
    const float* W1 = (const float*)d_in[2];
    const float* b1 = (const float*)d_in[3];
    const float* W2 = (const float*)d_in[4];
    const float* b2 = (const float*)d_in[5];
    float* o  = (float*)d_out;
    float* xp = (float*)d_ws;                 // 2048*256 floats = 2 MB
    float* yp = xp + (BB * N1) * DD;          // next 2 MB

    dim3 g1(32, 4, 2);               // (M/64, N/64, which) = 256 blocks
    proj_kernel<<<g1, 256, 0, stream>>>(x, y, W1, b1, xp, yp);

    dim3 g2(N2 / 32, N1 / 32, BB);   // 16 x 16 x 4 = 1024 four-wave blocks
    cross_kernel<<<g2, 256, 0, stream>>>(xp, yp, W2, b2, o);
}